// Round 2
// baseline (1937.042 us; speedup 1.0000x reference)
//
#include <hip/hip_runtime.h>
#include <hip/hip_bf16.h>
#include <stdint.h>

// Answer_Decoder: B=64, T=24, H=512, V=32000, E=256. All I/O float32.
// Attention is dead code (softmax over size-1 axis => ctx == cat(q,img)).
// Pipeline:
//   0) convert weights f32 -> bf16 in ws
//   1) build_x: X[1536][1280] = cat(embed[seq], question, image), bf16
//   2) G0 = X @ W_ih0^T + b_ih0 + b_hh0  (f32 [1536][2048])
//   3) 72x rec_step (t,l): gates GEMM (MFMA bf16) + fused LSTM pointwise
//   4) fc: h2_all[1536][512] @ fc_W^T + fc_b -> out[b][t][v] f32

typedef short bf16x8 __attribute__((ext_vector_type(8)));
typedef float f32x4 __attribute__((ext_vector_type(4)));

__device__ __forceinline__ unsigned short f2b(float f) {
    uint32_t u = __builtin_bit_cast(uint32_t, f);
    uint32_t r = u + 0x7FFFu + ((u >> 16) & 1u);
    return (unsigned short)(r >> 16);
}
__device__ __forceinline__ float sigmoidf(float x) {
    return 1.0f / (1.0f + expf(-x));
}

// ---------------- f32 -> bf16 convert ----------------
__global__ __launch_bounds__(256) void cvt_bf16(
    const float* __restrict__ src, unsigned short* __restrict__ dst, int n4)
{
    int i = blockIdx.x * 256 + threadIdx.x;
    if (i >= n4) return;
    f32x4 v = *(const f32x4*)&src[i * 4];
    unsigned short o[4];
    #pragma unroll
    for (int j = 0; j < 4; ++j) o[j] = f2b(v[j]);
    *(uint64_t*)&dst[i * 4] = *(uint64_t*)o;
}

// ---------------- build X ----------------
__global__ __launch_bounds__(256) void build_x(
    const float* __restrict__ qf,   // [64][512]
    const float* __restrict__ imf,  // [64][512]
    const int* __restrict__ seq,    // [64][24]
    const float* __restrict__ emb,  // [32000][256]
    unsigned short* __restrict__ X) // [1536][1280] bf16, row m = t*64+b
{
    int r = blockIdx.x;
    int t = r >> 6, b = r & 63;
    int tok = seq[b * 24 + t];
    for (int e = threadIdx.x; e < 1280; e += 256) {
        float v;
        if (e < 256)      v = emb[(size_t)tok * 256 + e];
        else if (e < 768) v = qf[b * 512 + (e - 256)];
        else              v = imf[b * 512 + (e - 768)];
        X[(size_t)r * 1280 + e] = f2b(v);
    }
}

// ---------------- generic 128x128 MFMA GEMM: C = A @ W^T + bias ----------------
// A [M][lda] bf16 row-major, W [N][ldb] bf16 row-major. K multiple of 64.
// OUT_MODE 0: f32 out [M][ldo], bias = bias0[n]+bias1[n] (f32)
// OUT_MODE 1: f32 out with m=(t*64+b) -> out[(b*24+t)*ldo + n], bias=bias0[n]
template<int OUT_MODE>
__global__ __launch_bounds__(256) void gemm128(
    const unsigned short* __restrict__ A, int lda,
    const unsigned short* __restrict__ W, int ldb,
    int K,
    const float* __restrict__ bias0,
    const float* __restrict__ bias1,
    float* __restrict__ outf, int ldo)
{
    __shared__ unsigned short lA[128 * 72];
    __shared__ unsigned short lB[128 * 72];
    const int m0 = blockIdx.x * 128, n0 = blockIdx.y * 128;
    const int tid = threadIdx.x;
    const int lane = tid & 63, wid = tid >> 6;
    const int wm = wid >> 1, wn = wid & 1;   // wave covers m: wm*64+, n: wn*64+

    f32x4 acc[4][4] = {};

    for (int kt = 0; kt < K; kt += 64) {
        #pragma unroll
        for (int c = 0; c < 4; ++c) {
            int chunk = tid + c * 256;           // 0..1023
            int row = chunk >> 3, kc = (chunk & 7) * 8;
            *(bf16x8*)&lA[row * 72 + kc] =
                *(const bf16x8*)&A[(size_t)(m0 + row) * lda + kt + kc];
            *(bf16x8*)&lB[row * 72 + kc] =
                *(const bf16x8*)&W[(size_t)(n0 + row) * ldb + kt + kc];
        }
        __syncthreads();
        #pragma unroll
        for (int ks = 0; ks < 64; ks += 32) {
            int kl = ks + ((lane >> 4) << 3);
            bf16x8 af[4], bfr[4];
            #pragma unroll
            for (int i = 0; i < 4; ++i)
                af[i] = *(const bf16x8*)&lA[(wm * 64 + i * 16 + (lane & 15)) * 72 + kl];
            #pragma unroll
            for (int j = 0; j < 4; ++j)
                bfr[j] = *(const bf16x8*)&lB[(wn * 64 + j * 16 + (lane & 15)) * 72 + kl];
            #pragma unroll
            for (int i = 0; i < 4; ++i)
                #pragma unroll
                for (int j = 0; j < 4; ++j)
                    acc[i][j] = __builtin_amdgcn_mfma_f32_16x16x32_bf16(
                        af[i], bfr[j], acc[i][j], 0, 0, 0);
        }
        __syncthreads();
    }

    #pragma unroll
    for (int i = 0; i < 4; ++i) {
        #pragma unroll
        for (int j = 0; j < 4; ++j) {
            int n = n0 + wn * 64 + j * 16 + (lane & 15);
            float bias;
            if (OUT_MODE == 0) bias = bias0[n] + bias1[n];
            else               bias = bias0[n];
            #pragma unroll
            for (int r = 0; r < 4; ++r) {
                int m = m0 + wm * 64 + i * 16 + ((lane >> 4) << 2) + r;
                float v = acc[i][j][r] + bias;
                if (OUT_MODE == 0) {
                    outf[(size_t)m * ldo + n] = v;
                } else {
                    int b = m & 63, t = m >> 6;
                    outf[(size_t)(b * 24 + t) * ldo + n] = v;
                }
            }
        }
    }
}

// ---------------- recurrence step: one (t, layer) ----------------
// gates[64][2048] = Acat @ [W0;W1]^T (+ pre or biases), then LSTM pointwise.
// Acat: k<512 -> A0[b*1536+k], k>=512 -> A1[b*1536+k-512].  (bf16)
// Block j0 owns all 4 gates for j in [j0,j0+32) => i,f,g,o lane-local.
__global__ __launch_bounds__(256) void rec_step(
    const unsigned short* __restrict__ A0,
    const unsigned short* __restrict__ A1,
    const unsigned short* __restrict__ W0,  // bf16 [2048][512] first K-half
    const unsigned short* __restrict__ W1,  // second K-half (or unused)
    int K,                                  // 512 or 1024
    const float* __restrict__ pre,          // G0 row block, or nullptr
    const float* __restrict__ bih,
    const float* __restrict__ bhh,
    float* __restrict__ cst,                // + l*512, row stride 1536
    unsigned short* __restrict__ hout,      // + l*512, row stride 1536, bf16
    unsigned short* __restrict__ h2out)     // + t*64*512, stride 512, or nullptr
{
    __shared__ unsigned short lA[64 * 136];
    __shared__ unsigned short lB[128 * 136];
    const int j0 = blockIdx.x * 32;
    const int tid = threadIdx.x;
    const int lane = tid & 63, wid = tid >> 6;
    const int wm = wid >> 1, wn = wid & 1;  // wave: m rows wm*32+, j-cols wn*16+

    f32x4 acc[2][4] = {};

    for (int kt = 0; kt < K; kt += 128) {
        // stage A: 64 rows x 128 k = 1024 chunks (4 per thread)
        #pragma unroll
        for (int c = 0; c < 4; ++c) {
            int chunk = tid + c * 256;
            int row = chunk >> 4, kc = (chunk & 15) * 8;
            int kg = kt + kc;
            const unsigned short* src = (kg < 512)
                ? &A0[(size_t)row * 1536 + kg]
                : &A1[(size_t)row * 1536 + (kg - 512)];
            *(bf16x8*)&lA[row * 136 + kc] = *(const bf16x8*)src;
        }
        // stage B: 128 n_local rows x 128 k = 2048 chunks (8 per thread)
        #pragma unroll
        for (int c = 0; c < 8; ++c) {
            int chunk = tid + c * 256;
            int row = chunk >> 4, kc = (chunk & 15) * 8;
            int kg = kt + kc;
            int wrow = ((row >> 5) << 9) + j0 + (row & 31);  // q*512 + j
            const unsigned short* src = (kg < 512)
                ? &W0[(size_t)wrow * 512 + kg]
                : &W1[(size_t)wrow * 512 + (kg - 512)];
            *(bf16x8*)&lB[row * 136 + kc] = *(const bf16x8*)src;
        }
        __syncthreads();
        #pragma unroll
        for (int ks = 0; ks < 128; ks += 32) {
            int kl = ks + ((lane >> 4) << 3);
            bf16x8 af[2], bfr[4];
            #pragma unroll
            for (int i = 0; i < 2; ++i)
                af[i] = *(const bf16x8*)&lA[(wm * 32 + i * 16 + (lane & 15)) * 136 + kl];
            #pragma unroll
            for (int q = 0; q < 4; ++q)
                bfr[q] = *(const bf16x8*)&lB[(q * 32 + wn * 16 + (lane & 15)) * 136 + kl];
            #pragma unroll
            for (int i = 0; i < 2; ++i)
                #pragma unroll
                for (int q = 0; q < 4; ++q)
                    acc[i][q] = __builtin_amdgcn_mfma_f32_16x16x32_bf16(
                        af[i], bfr[q], acc[i][q], 0, 0, 0);
        }
        __syncthreads();
    }

    const int j = j0 + wn * 16 + (lane & 15);
    #pragma unroll
    for (int i = 0; i < 2; ++i) {
        #pragma unroll
        for (int r = 0; r < 4; ++r) {
            int b = wm * 32 + i * 16 + ((lane >> 4) << 2) + r;
            float g[4];
            #pragma unroll
            for (int q = 0; q < 4; ++q) {
                float p;
                if (pre) p = pre[(size_t)b * 2048 + q * 512 + j];
                else     p = bih[q * 512 + j] + bhh[q * 512 + j];
                g[q] = acc[i][q][r] + p;
            }
            float ig = sigmoidf(g[0]);
            float fg = sigmoidf(g[1]);
            float gg = tanhf(g[2]);
            float og = sigmoidf(g[3]);
            size_t cidx = (size_t)b * 1536 + j;
            float cn = fg * cst[cidx] + ig * gg;
            cst[cidx] = cn;
            float h = og * tanhf(cn);
            unsigned short hb = f2b(h);
            hout[(size_t)b * 1536 + j] = hb;
            if (h2out) h2out[(size_t)b * 512 + j] = hb;
        }
    }
}

// ---------------- launch ----------------
extern "C" void kernel_launch(void* const* d_in, const int* in_sizes, int n_in,
                              void* d_out, int out_size, void* d_ws, size_t ws_size,
                              hipStream_t stream) {
    const float* qf  = (const float*)d_in[0];
    const float* imf = (const float*)d_in[1];
    const int*   seq = (const int*)d_in[2];
    const float* emb = (const float*)d_in[3];
    // d_in[4..6] (attn_W, attn_b, v_W) are dead code in the reference
    const float* fcW = (const float*)d_in[7];
    const float* fcb = (const float*)d_in[8];
    const float* Wih[3] = {(const float*)d_in[9],  (const float*)d_in[13], (const float*)d_in[17]};
    const float* Whh[3] = {(const float*)d_in[10], (const float*)d_in[14], (const float*)d_in[18]};
    const float* bih[3] = {(const float*)d_in[11], (const float*)d_in[15], (const float*)d_in[19]};
    const float* bhh[3] = {(const float*)d_in[12], (const float*)d_in[16], (const float*)d_in[20]};

    char* ws = (char*)d_ws;
    unsigned short* X     = (unsigned short*)(ws + 0);         // 1536*1280*2 = 3,932,160
    float*          G0    = (float*)(ws + 3932160);            // 1536*2048*4 = 12,582,912
    unsigned short* hbuf  = (unsigned short*)(ws + 16515072);  // 2*64*1536*2 = 393,216
    float*          cst   = (float*)(ws + 16908288);           // 64*1536*4   = 393,216
    unsigned short* h2all = (unsigned short*)(ws + 17301504);  // 24*64*512*2 = 1,572,864
    unsigned short* Wb    = (unsigned short*)(ws + 18874368);  // bf16 weights below
    unsigned short* Wih0b = Wb;                                // 2048*1280
    unsigned short* Whh0b = Wih0b + 2048 * 1280;               // 2048*512
    unsigned short* Wih1b = Whh0b + 2048 * 512;
    unsigned short* Whh1b = Wih1b + 2048 * 512;
    unsigned short* Wih2b = Whh1b + 2048 * 512;
    unsigned short* Whh2b = Wih2b + 2048 * 512;
    unsigned short* fcWb  = Whh2b + 2048 * 512;                // 32000*512

    hipMemsetAsync(hbuf, 0, 393216, stream);
    hipMemsetAsync(cst, 0, 393216, stream);

    // weight conversions f32 -> bf16
    {
        int n4;
        n4 = 2048 * 1280 / 4; cvt_bf16<<<(n4 + 255) / 256, 256, 0, stream>>>(Wih[0], Wih0b, n4);
        n4 = 2048 * 512 / 4;
        cvt_bf16<<<(n4 + 255) / 256, 256, 0, stream>>>(Whh[0], Whh0b, n4);
        cvt_bf16<<<(n4 + 255) / 256, 256, 0, stream>>>(Wih[1], Wih1b, n4);
        cvt_bf16<<<(n4 + 255) / 256, 256, 0, stream>>>(Whh[1], Whh1b, n4);
        cvt_bf16<<<(n4 + 255) / 256, 256, 0, stream>>>(Wih[2], Wih2b, n4);
        cvt_bf16<<<(n4 + 255) / 256, 256, 0, stream>>>(Whh[2], Whh2b, n4);
        n4 = 32000 * 512 / 4; cvt_bf16<<<(n4 + 255) / 256, 256, 0, stream>>>(fcW, fcWb, n4);
    }

    build_x<<<1536, 256, 0, stream>>>(qf, imf, seq, emb, X);

    // G0 = X @ W_ih0^T + b_ih0 + b_hh0 : M=1536, N=2048, K=1280
    gemm128<0><<<dim3(12, 16), 256, 0, stream>>>(
        X, 1280, Wih0b, 1280, 1280, bih[0], bhh[0], G0, 2048);

    const unsigned short* WihB[3] = {Wih0b, Wih1b, Wih2b};
    const unsigned short* WhhB[3] = {Whh0b, Whh1b, Whh2b};

    for (int t = 0; t < 24; ++t) {
        int p = t & 1;
        unsigned short* hcur  = hbuf + (size_t)p * 64 * 1536;
        unsigned short* hprev = hbuf + (size_t)(p ^ 1) * 64 * 1536;
        for (int l = 0; l < 3; ++l) {
            const unsigned short *A0, *A1, *W0, *W1;
            int K;
            const float* pre = nullptr;
            if (l == 0) {
                A0 = hprev; A1 = nullptr; W0 = WhhB[0]; W1 = nullptr; K = 512;
                pre = G0 + (size_t)t * 64 * 2048;
            } else {
                A0 = hcur + (l - 1) * 512; A1 = hprev + l * 512;
                W0 = WihB[l]; W1 = WhhB[l]; K = 1024;
            }
            rec_step<<<16, 256, 0, stream>>>(
                A0, A1, W0, W1, K, pre, bih[l], bhh[l],
                cst + l * 512, hcur + l * 512,
                (l == 2) ? (h2all + (size_t)t * 64 * 512) : nullptr);
        }
    }

    // logits: h2all[1536][512] @ fc_W^T + fc_b -> out[b][t][32000] f32
    gemm128<1><<<dim3(12, 250), 256, 0, stream>>>(
        h2all, 512, fcWb, 512, 512, fcb, nullptr, (float*)d_out, 32000);
}

// Round 3
// 571.023 us; speedup vs baseline: 3.3922x; 3.3922x over previous
//
#include <hip/hip_runtime.h>
#include <hip/hip_bf16.h>
#include <stdint.h>

// Answer_Decoder: B=64, T=24, H=512, V=32000, E=256. All I/O float32.
// Attention is dead code (softmax over size-1 axis => ctx == cat(q,img)).
// Pipeline:
//   0) cvt Wih0/fcW f32->bf16; pack recurrent weights bf16 per-block
//   1) build_x: X[1536][1280] bf16
//   2) G0 = X @ W_ih0^T + b_ih0 + b_hh0 (f32, gemm128<0>)
//   3) lstm_wave: ONE persistent kernel, 96 blocks (32/layer), (t,layer)
//      wavefront with device-scope flag sync; c in registers; h per-t.
//   4) fc: hst[2] @ fc_W^T + fc_b -> out[b][t][v] f32 (gemm128<1>, XCD swizzle)

typedef short bf16x8 __attribute__((ext_vector_type(8)));
typedef float f32x4 __attribute__((ext_vector_type(4)));

#define NBLK_L 32   // blocks per layer in lstm_wave

__device__ __forceinline__ unsigned short f2b(float f) {
    uint32_t u = __builtin_bit_cast(uint32_t, f);
    uint32_t r = u + 0x7FFFu + ((u >> 16) & 1u);
    return (unsigned short)(r >> 16);
}
__device__ __forceinline__ float sigmoidf(float x) {
    return 1.0f / (1.0f + expf(-x));
}

// ---------------- f32 -> bf16 convert ----------------
__global__ __launch_bounds__(256) void cvt_bf16(
    const float* __restrict__ src, unsigned short* __restrict__ dst, int n4)
{
    int i = blockIdx.x * 256 + threadIdx.x;
    if (i >= n4) return;
    f32x4 v = *(const f32x4*)&src[i * 4];
    unsigned short o[4];
    #pragma unroll
    for (int j = 0; j < 4; ++j) o[j] = f2b(v[j]);
    *(uint64_t*)&dst[i * 4] = *(uint64_t*)o;
}

// ---------------- pack recurrent weights (bf16, per-block contiguous) -------
// Wpk layout: l0 [32][64][512] ; l1 [32][64][1024] ; l2 [32][64][1024]
// block row r in [0,64): gate q=r>>4, jj=r&15; source gate-row = q*512+lbid*16+jj
__global__ __launch_bounds__(128) void pack_w(
    const float* __restrict__ Whh0,
    const float* __restrict__ Wih1, const float* __restrict__ Whh1,
    const float* __restrict__ Wih2, const float* __restrict__ Whh2,
    unsigned short* __restrict__ Wpk)
{
    int gid = blockIdx.x;                 // 3*32*64 = 6144
    int layer = gid / (32 * 64);
    int rem = gid % (32 * 64);
    int lbid = rem >> 6, r = rem & 63;
    int q = r >> 4, jj = r & 15;
    int grow = q * 512 + lbid * 16 + jj;
    int K = (layer == 0) ? 512 : 1024;
    size_t wbase = (layer == 0) ? 0
                 : (layer == 1) ? (size_t)32 * 64 * 512
                                : (size_t)32 * 64 * 512 + (size_t)32 * 64 * 1024;
    unsigned short* dst = Wpk + wbase + ((size_t)lbid * 64 + r) * K;
    const float *s0, *s1 = nullptr;
    if (layer == 0)      { s0 = Whh0 + (size_t)grow * 512; }
    else if (layer == 1) { s0 = Wih1 + (size_t)grow * 512; s1 = Whh1 + (size_t)grow * 512; }
    else                 { s0 = Wih2 + (size_t)grow * 512; s1 = Whh2 + (size_t)grow * 512; }
    {
        int k4 = threadIdx.x;             // 128 threads x 4 = 512
        f32x4 v = *(const f32x4*)&s0[k4 * 4];
        unsigned short o[4];
        #pragma unroll
        for (int j = 0; j < 4; ++j) o[j] = f2b(v[j]);
        *(uint64_t*)&dst[k4 * 4] = *(uint64_t*)o;
    }
    if (s1) {
        int k4 = threadIdx.x;
        f32x4 v = *(const f32x4*)&s1[k4 * 4];
        unsigned short o[4];
        #pragma unroll
        for (int j = 0; j < 4; ++j) o[j] = f2b(v[j]);
        *(uint64_t*)&dst[512 + k4 * 4] = *(uint64_t*)o;
    }
}

// ---------------- build X ----------------
__global__ __launch_bounds__(256) void build_x(
    const float* __restrict__ qf,   // [64][512]
    const float* __restrict__ imf,  // [64][512]
    const int* __restrict__ seq,    // [64][24]
    const float* __restrict__ emb,  // [32000][256]
    unsigned short* __restrict__ X) // [1536][1280] bf16, row m = t*64+b
{
    int r = blockIdx.x;
    int t = r >> 6, b = r & 63;
    int tok = seq[b * 24 + t];
    for (int e = threadIdx.x; e < 1280; e += 256) {
        float v;
        if (e < 256)      v = emb[(size_t)tok * 256 + e];
        else if (e < 768) v = qf[b * 512 + (e - 256)];
        else              v = imf[b * 512 + (e - 768)];
        X[(size_t)r * 1280 + e] = f2b(v);
    }
}

// ---------------- 128x128 MFMA GEMM: C = A @ W^T + bias ----------------
// 1D grid (nwg = mblocks * nblocks, divisible by 8), XCD-bijective remap.
// OUT_MODE 0: f32 out [M][ldo], bias = bias0[n]+bias1[n]
// OUT_MODE 1: f32 out with m=(t*64+b) -> out[(b*24+t)*ldo + n], bias=bias0[n]
template<int OUT_MODE>
__global__ __launch_bounds__(256) void gemm128(
    const unsigned short* __restrict__ A, int lda,
    const unsigned short* __restrict__ W, int ldb,
    int K,
    const float* __restrict__ bias0,
    const float* __restrict__ bias1,
    float* __restrict__ outf, int ldo, int mblocks, int xcdq)
{
    __shared__ unsigned short lA[128 * 72];
    __shared__ unsigned short lB[128 * 72];
    int lin = blockIdx.x;
    int wg = (lin & 7) * xcdq + (lin >> 3);     // contiguous chunk per XCD
    const int m0 = (wg % mblocks) * 128, n0 = (wg / mblocks) * 128;
    const int tid = threadIdx.x;
    const int lane = tid & 63, wid = tid >> 6;
    const int wm = wid >> 1, wn = wid & 1;

    f32x4 acc[4][4] = {};

    for (int kt = 0; kt < K; kt += 64) {
        #pragma unroll
        for (int c = 0; c < 4; ++c) {
            int chunk = tid + c * 256;
            int row = chunk >> 3, kc = (chunk & 7) * 8;
            *(bf16x8*)&lA[row * 72 + kc] =
                *(const bf16x8*)&A[(size_t)(m0 + row) * lda + kt + kc];
            *(bf16x8*)&lB[row * 72 + kc] =
                *(const bf16x8*)&W[(size_t)(n0 + row) * ldb + kt + kc];
        }
        __syncthreads();
        #pragma unroll
        for (int ks = 0; ks < 64; ks += 32) {
            int kl = ks + ((lane >> 4) << 3);
            bf16x8 af[4], bfr[4];
            #pragma unroll
            for (int i = 0; i < 4; ++i)
                af[i] = *(const bf16x8*)&lA[(wm * 64 + i * 16 + (lane & 15)) * 72 + kl];
            #pragma unroll
            for (int j = 0; j < 4; ++j)
                bfr[j] = *(const bf16x8*)&lB[(wn * 64 + j * 16 + (lane & 15)) * 72 + kl];
            #pragma unroll
            for (int i = 0; i < 4; ++i)
                #pragma unroll
                for (int j = 0; j < 4; ++j)
                    acc[i][j] = __builtin_amdgcn_mfma_f32_16x16x32_bf16(
                        af[i], bfr[j], acc[i][j], 0, 0, 0);
        }
        __syncthreads();
    }

    #pragma unroll
    for (int i = 0; i < 4; ++i) {
        #pragma unroll
        for (int j = 0; j < 4; ++j) {
            int n = n0 + wn * 64 + j * 16 + (lane & 15);
            float bias = (OUT_MODE == 0) ? bias0[n] + bias1[n] : bias0[n];
            #pragma unroll
            for (int r = 0; r < 4; ++r) {
                int m = m0 + wm * 64 + i * 16 + ((lane >> 4) << 2) + r;
                float v = acc[i][j][r] + bias;
                if (OUT_MODE == 0) {
                    outf[(size_t)m * ldo + n] = v;
                } else {
                    int b = m & 63, t = m >> 6;
                    outf[(size_t)(b * 24 + t) * ldo + n] = v;
                }
            }
        }
    }
}

// ---------------- persistent wavefront LSTM recurrence ----------------
// 96 blocks x 256 threads. Block bid: layer = bid>>5, lbid = bid&31,
// j-slice = [lbid*16, lbid*16+16). Per cell (t,layer): gates[64 x 64rows]
// = A[64xK] @ Wblk[64xK]^T ; A direct-from-global, Wblk via LDS.
// h state: hst[3][25][64][512] bf16 (slot 0 = zeros); c in registers.
// flags[3][24]: blocks completed per cell; release-add / acquire-spin.
__global__ __launch_bounds__(256) void lstm_wave(
    const unsigned short* __restrict__ Wpk,
    const float* __restrict__ G0,            // [24][64][2048]
    const float* __restrict__ bih1, const float* __restrict__ bhh1,
    const float* __restrict__ bih2, const float* __restrict__ bhh2,
    unsigned short* __restrict__ hst,        // [3][25][64][512]
    unsigned int* __restrict__ flags)        // [3][24]
{
    __shared__ unsigned short lB[64 * 264];
    const int bid = blockIdx.x;
    const int layer = bid >> 5;
    const int lbid = bid & 31;
    const int j0 = lbid * 16;
    const int tid = threadIdx.x;
    const int lane = tid & 63, w = tid >> 6;       // wave w: batch rows w*16..
    const int lrow = lane & 15, lk = (lane >> 4) * 8;

    const int K = (layer == 0) ? 512 : 1024;
    const size_t wbase = (layer == 0) ? 0
                       : (layer == 1) ? (size_t)32 * 64 * 512
                                      : (size_t)32 * 64 * 512 + (size_t)32 * 64 * 1024;
    const unsigned short* Wblk = Wpk + wbase + (size_t)lbid * 64 * K;

    unsigned short* hl = hst + (size_t)layer * 25 * 64 * 512;
    const unsigned short* hlow =
        (layer > 0) ? hst + (size_t)(layer - 1) * 25 * 64 * 512 : nullptr;

    // per-lane bias (layers 1,2), constant over t: j = j0+lrow, gates q
    float pb[4] = {0.f, 0.f, 0.f, 0.f};
    if (layer == 1) {
        #pragma unroll
        for (int q = 0; q < 4; ++q)
            pb[q] = bih1[q * 512 + j0 + lrow] + bhh1[q * 512 + j0 + lrow];
    } else if (layer == 2) {
        #pragma unroll
        for (int q = 0; q < 4; ++q)
            pb[q] = bih2[q * 512 + j0 + lrow] + bhh2[q * 512 + j0 + lrow];
    }

    float creg[4] = {0.f, 0.f, 0.f, 0.f};

    for (int t = 0; t < 24; ++t) {
        // ---- wait for dependencies (acquire)
        if (tid == 0) {
            if (layer == 0) {
                if (t > 0)
                    while (__hip_atomic_load(&flags[0 * 24 + t - 1], __ATOMIC_ACQUIRE,
                                             __HIP_MEMORY_SCOPE_AGENT) < NBLK_L)
                        __builtin_amdgcn_s_sleep(2);
            } else {
                while (__hip_atomic_load(&flags[(layer - 1) * 24 + t], __ATOMIC_ACQUIRE,
                                         __HIP_MEMORY_SCOPE_AGENT) < NBLK_L)
                    __builtin_amdgcn_s_sleep(2);
                if (t > 0)
                    while (__hip_atomic_load(&flags[layer * 24 + t - 1], __ATOMIC_ACQUIRE,
                                             __HIP_MEMORY_SCOPE_AGENT) < NBLK_L)
                        __builtin_amdgcn_s_sleep(2);
            }
            __threadfence();   // L1/L2 invalidate so h reads see remote writes
        }
        __syncthreads();

        const unsigned short* A0 = (layer == 0)
            ? hl + (size_t)t * 64 * 512              // h_{0,t-1}
            : hlow + (size_t)(t + 1) * 64 * 512;     // h_{l-1,t}
        const unsigned short* A1 = (layer == 0)
            ? nullptr
            : hl + (size_t)t * 64 * 512;             // h_{l,t-1}

        f32x4 acc[4] = {};

        for (int kt = 0; kt < K; kt += 256) {
            // stage W chunk [64 rows][256 k] -> LDS (pad 264)
            #pragma unroll
            for (int c = 0; c < 8; ++c) {
                int v = tid + c * 256;               // 0..2047
                int row = v >> 5, kc = (v & 31) * 8;
                *(bf16x8*)&lB[row * 264 + kc] =
                    *(const bf16x8*)&Wblk[(size_t)row * K + kt + kc];
            }
            __syncthreads();
            #pragma unroll
            for (int ks = 0; ks < 256; ks += 32) {
                int kg = kt + ks + lk;
                const unsigned short* ap = (kg < 512)
                    ? &A0[(size_t)(w * 16 + lrow) * 512 + kg]
                    : &A1[(size_t)(w * 16 + lrow) * 512 + (kg - 512)];
                bf16x8 af = *(const bf16x8*)ap;
                #pragma unroll
                for (int q = 0; q < 4; ++q) {
                    bf16x8 bq = *(const bf16x8*)&lB[(q * 16 + lrow) * 264 + ks + lk];
                    acc[q] = __builtin_amdgcn_mfma_f32_16x16x32_bf16(af, bq, acc[q], 0, 0, 0);
                }
            }
            __syncthreads();
        }

        // ---- fused LSTM pointwise epilogue
        int j = j0 + lrow;
        #pragma unroll
        for (int r = 0; r < 4; ++r) {
            int b = w * 16 + ((lane >> 4) << 2) + r;
            float g[4];
            #pragma unroll
            for (int q = 0; q < 4; ++q) {
                float p = (layer == 0)
                    ? G0[((size_t)t * 64 + b) * 2048 + q * 512 + j]
                    : pb[q];
                g[q] = acc[q][r] + p;
            }
            float ig = sigmoidf(g[0]);
            float fg = sigmoidf(g[1]);
            float gg = tanhf(g[2]);
            float og = sigmoidf(g[3]);
            float cn = fg * creg[r] + ig * gg;
            creg[r] = cn;
            float h = og * tanhf(cn);
            hl[((size_t)(t + 1) * 64 + b) * 512 + j] = f2b(h);
        }
        __syncthreads();           // all waves' stores drained (vmcnt before barrier)
        if (tid == 0) {
            __hip_atomic_fetch_add(&flags[layer * 24 + t], 1u, __ATOMIC_RELEASE,
                                   __HIP_MEMORY_SCOPE_AGENT);
        }
    }
}

// ---------------- launch ----------------
extern "C" void kernel_launch(void* const* d_in, const int* in_sizes, int n_in,
                              void* d_out, int out_size, void* d_ws, size_t ws_size,
                              hipStream_t stream) {
    const float* qf  = (const float*)d_in[0];
    const float* imf = (const float*)d_in[1];
    const int*   seq = (const int*)d_in[2];
    const float* emb = (const float*)d_in[3];
    // d_in[4..6] dead code
    const float* fcW = (const float*)d_in[7];
    const float* fcb = (const float*)d_in[8];
    const float* Wih[3] = {(const float*)d_in[9],  (const float*)d_in[13], (const float*)d_in[17]};
    const float* Whh[3] = {(const float*)d_in[10], (const float*)d_in[14], (const float*)d_in[18]};
    const float* bih[3] = {(const float*)d_in[11], (const float*)d_in[15], (const float*)d_in[19]};
    const float* bhh[3] = {(const float*)d_in[12], (const float*)d_in[16], (const float*)d_in[20]};

    char* ws = (char*)d_ws;
    unsigned short* X     = (unsigned short*)(ws + 0);          // 3,932,160
    float*          G0    = (float*)(ws + 3932160);             // 12,582,912
    unsigned short* hst   = (unsigned short*)(ws + 16515072);   // 4,915,200
    unsigned int*   flags = (unsigned int*)(ws + 21430272);     // 288 (pad to 512)
    unsigned short* Wpk   = (unsigned short*)(ws + 21430784);   // 10,485,760
    unsigned short* Wih0b = (unsigned short*)(ws + 31916544);   // 5,242,880
    unsigned short* fcWb  = (unsigned short*)(ws + 37159424);   // 32,768,000  (end ~70MB)

    // zero: flags + h slot 0 of each layer
    hipMemsetAsync(flags, 0, 512, stream);
    for (int l = 0; l < 3; ++l)
        hipMemsetAsync(hst + (size_t)l * 25 * 64 * 512, 0, 64 * 512 * 2, stream);

    // weight conversions
    { int n4 = 2048 * 1280 / 4;
      cvt_bf16<<<(n4 + 255) / 256, 256, 0, stream>>>(Wih[0], Wih0b, n4); }
    { int n4 = 32000 * 512 / 4;
      cvt_bf16<<<(n4 + 255) / 256, 256, 0, stream>>>(fcW, fcWb, n4); }
    pack_w<<<3 * 32 * 64, 128, 0, stream>>>(Whh[0], Wih[1], Whh[1], Wih[2], Whh[2], Wpk);

    build_x<<<1536, 256, 0, stream>>>(qf, imf, seq, emb, X);

    // G0 = X @ W_ih0^T + b_ih0 + b_hh0 : M=1536, N=2048, K=1280 -> 12x16=192 wg
    gemm128<0><<<192, 256, 0, stream>>>(
        X, 1280, Wih0b, 1280, 1280, bih[0], bhh[0], G0, 2048, 12, 192 / 8);

    lstm_wave<<<96, 256, 0, stream>>>(
        Wpk, G0, bih[1], bhh[1], bih[2], bhh[2], hst, flags);

    // logits: hst[2] slots 1..24 = h2 rows m=t*64+b ; M=1536,N=32000,K=512
    const unsigned short* h2 = hst + (size_t)2 * 25 * 64 * 512 + 64 * 512;
    gemm128<1><<<3000, 256, 0, stream>>>(
        h2, 512, fcWb, 512, 512, fcb, nullptr, (float*)d_out, 32000, 12, 3000 / 8);
}

// Round 4
// 505.565 us; speedup vs baseline: 3.8314x; 1.1295x over previous
//
#include <hip/hip_runtime.h>
#include <hip/hip_bf16.h>
#include <stdint.h>

// Answer_Decoder: B=64, T=24, H=512, V=32000, E=256. All I/O float32.
// Attention is dead code (softmax over size-1 axis => ctx == cat(q,img)).
// Pipeline:
//   0) cvt Wih0/fcW f32->bf16; pack recurrent weights bf16 per-block
//   1) build_x: X[1536][1280] bf16
//   2) G0 = X @ W_ih0^T + b_ih0 + b_hh0 (f32, gemm128<0>)
//   3) lstm_wave: ONE persistent kernel, 96 blocks (32/layer), (t,layer)
//      wavefront; single-writer release/acquire flags; W persistent in LDS;
//      c in registers; h per-t slots (no WAR hazards).
//   4) fc: hst[2] @ fc_W^T + fc_b -> out[b][t][v] f32 (gemm128<1>, XCD swizzle)

typedef short bf16x8 __attribute__((ext_vector_type(8)));
typedef float f32x4 __attribute__((ext_vector_type(4)));

#define NBLK_L 32   // blocks per layer in lstm_wave

__device__ __forceinline__ unsigned short f2b(float f) {
    uint32_t u = __builtin_bit_cast(uint32_t, f);
    uint32_t r = u + 0x7FFFu + ((u >> 16) & 1u);
    return (unsigned short)(r >> 16);
}
__device__ __forceinline__ float sigmoidf(float x) {
    return 1.0f / (1.0f + expf(-x));
}

// ---------------- f32 -> bf16 convert ----------------
__global__ __launch_bounds__(256) void cvt_bf16(
    const float* __restrict__ src, unsigned short* __restrict__ dst, int n4)
{
    int i = blockIdx.x * 256 + threadIdx.x;
    if (i >= n4) return;
    f32x4 v = *(const f32x4*)&src[i * 4];
    unsigned short o[4];
    #pragma unroll
    for (int j = 0; j < 4; ++j) o[j] = f2b(v[j]);
    *(uint64_t*)&dst[i * 4] = *(uint64_t*)o;
}

// ---------------- pack recurrent weights (bf16, per-block contiguous) -------
// Wpk layout: l0 [32][64][512] ; l1 [32][64][1024] ; l2 [32][64][1024]
// block row r in [0,64): gate q=r>>4, jj=r&15; source gate-row = q*512+lbid*16+jj
__global__ __launch_bounds__(128) void pack_w(
    const float* __restrict__ Whh0,
    const float* __restrict__ Wih1, const float* __restrict__ Whh1,
    const float* __restrict__ Wih2, const float* __restrict__ Whh2,
    unsigned short* __restrict__ Wpk)
{
    int gid = blockIdx.x;                 // 3*32*64 = 6144
    int layer = gid / (32 * 64);
    int rem = gid % (32 * 64);
    int lbid = rem >> 6, r = rem & 63;
    int q = r >> 4, jj = r & 15;
    int grow = q * 512 + lbid * 16 + jj;
    int K = (layer == 0) ? 512 : 1024;
    size_t wbase = (layer == 0) ? 0
                 : (layer == 1) ? (size_t)32 * 64 * 512
                                : (size_t)32 * 64 * 512 + (size_t)32 * 64 * 1024;
    unsigned short* dst = Wpk + wbase + ((size_t)lbid * 64 + r) * K;
    const float *s0, *s1 = nullptr;
    if (layer == 0)      { s0 = Whh0 + (size_t)grow * 512; }
    else if (layer == 1) { s0 = Wih1 + (size_t)grow * 512; s1 = Whh1 + (size_t)grow * 512; }
    else                 { s0 = Wih2 + (size_t)grow * 512; s1 = Whh2 + (size_t)grow * 512; }
    {
        int k4 = threadIdx.x;             // 128 threads x 4 = 512
        f32x4 v = *(const f32x4*)&s0[k4 * 4];
        unsigned short o[4];
        #pragma unroll
        for (int j = 0; j < 4; ++j) o[j] = f2b(v[j]);
        *(uint64_t*)&dst[k4 * 4] = *(uint64_t*)o;
    }
    if (s1) {
        int k4 = threadIdx.x;
        f32x4 v = *(const f32x4*)&s1[k4 * 4];
        unsigned short o[4];
        #pragma unroll
        for (int j = 0; j < 4; ++j) o[j] = f2b(v[j]);
        *(uint64_t*)&dst[512 + k4 * 4] = *(uint64_t*)o;
    }
}

// ---------------- build X ----------------
__global__ __launch_bounds__(256) void build_x(
    const float* __restrict__ qf,   // [64][512]
    const float* __restrict__ imf,  // [64][512]
    const int* __restrict__ seq,    // [64][24]
    const float* __restrict__ emb,  // [32000][256]
    unsigned short* __restrict__ X) // [1536][1280] bf16, row m = t*64+b
{
    int r = blockIdx.x;
    int t = r >> 6, b = r & 63;
    int tok = seq[b * 24 + t];
    for (int e = threadIdx.x; e < 1280; e += 256) {
        float v;
        if (e < 256)      v = emb[(size_t)tok * 256 + e];
        else if (e < 768) v = qf[b * 512 + (e - 256)];
        else              v = imf[b * 512 + (e - 768)];
        X[(size_t)r * 1280 + e] = f2b(v);
    }
}

// ---------------- 128x128 MFMA GEMM: C = A @ W^T + bias ----------------
// 1D grid (nwg = mblocks * nblocks, divisible by 8), XCD-bijective remap.
// OUT_MODE 0: f32 out [M][ldo], bias = bias0[n]+bias1[n]
// OUT_MODE 1: f32 out with m=(t*64+b) -> out[(b*24+t)*ldo + n], bias=bias0[n]
template<int OUT_MODE>
__global__ __launch_bounds__(256) void gemm128(
    const unsigned short* __restrict__ A, int lda,
    const unsigned short* __restrict__ W, int ldb,
    int K,
    const float* __restrict__ bias0,
    const float* __restrict__ bias1,
    float* __restrict__ outf, int ldo, int mblocks, int xcdq)
{
    __shared__ unsigned short lA[128 * 72];
    __shared__ unsigned short lB[128 * 72];
    int lin = blockIdx.x;
    int wg = (lin & 7) * xcdq + (lin >> 3);     // contiguous chunk per XCD
    const int m0 = (wg % mblocks) * 128, n0 = (wg / mblocks) * 128;
    const int tid = threadIdx.x;
    const int lane = tid & 63, wid = tid >> 6;
    const int wm = wid >> 1, wn = wid & 1;

    f32x4 acc[4][4] = {};

    for (int kt = 0; kt < K; kt += 64) {
        #pragma unroll
        for (int c = 0; c < 4; ++c) {
            int chunk = tid + c * 256;
            int row = chunk >> 3, kc = (chunk & 7) * 8;
            *(bf16x8*)&lA[row * 72 + kc] =
                *(const bf16x8*)&A[(size_t)(m0 + row) * lda + kt + kc];
            *(bf16x8*)&lB[row * 72 + kc] =
                *(const bf16x8*)&W[(size_t)(n0 + row) * ldb + kt + kc];
        }
        __syncthreads();
        #pragma unroll
        for (int ks = 0; ks < 64; ks += 32) {
            int kl = ks + ((lane >> 4) << 3);
            bf16x8 af[4], bfr[4];
            #pragma unroll
            for (int i = 0; i < 4; ++i)
                af[i] = *(const bf16x8*)&lA[(wm * 64 + i * 16 + (lane & 15)) * 72 + kl];
            #pragma unroll
            for (int j = 0; j < 4; ++j)
                bfr[j] = *(const bf16x8*)&lB[(wn * 64 + j * 16 + (lane & 15)) * 72 + kl];
            #pragma unroll
            for (int i = 0; i < 4; ++i)
                #pragma unroll
                for (int j = 0; j < 4; ++j)
                    acc[i][j] = __builtin_amdgcn_mfma_f32_16x16x32_bf16(
                        af[i], bfr[j], acc[i][j], 0, 0, 0);
        }
        __syncthreads();
    }

    #pragma unroll
    for (int i = 0; i < 4; ++i) {
        #pragma unroll
        for (int j = 0; j < 4; ++j) {
            int n = n0 + wn * 64 + j * 16 + (lane & 15);
            float bias = (OUT_MODE == 0) ? bias0[n] + bias1[n] : bias0[n];
            #pragma unroll
            for (int r = 0; r < 4; ++r) {
                int m = m0 + wm * 64 + i * 16 + ((lane >> 4) << 2) + r;
                float v = acc[i][j][r] + bias;
                if (OUT_MODE == 0) {
                    outf[(size_t)m * ldo + n] = v;
                } else {
                    int b = m & 63, t = m >> 6;
                    outf[(size_t)(b * 24 + t) * ldo + n] = v;
                }
            }
        }
    }
}

// ---------------- persistent wavefront LSTM recurrence ----------------
// 96 blocks x 256 threads. Block bid: layer = bid>>5, lbid = bid&31,
// j-slice = [lbid*16, lbid*16+16). Per cell (t,layer): gates[64 x 64rows]
// = A[64xK] @ Wblk[64xK]^T ; A direct-from-global; W PERSISTENT in LDS.
// h state: hst[3][25][64][512] bf16 (slot 0 = zeros); c in registers.
// flags[3][24][32]: SINGLE-WRITER per block; release-store / acquire-poll.
__global__ __launch_bounds__(256, 1) void lstm_wave(
    const unsigned short* __restrict__ Wpk,
    const float* __restrict__ G0,            // [24][64][2048]
    const float* __restrict__ bih1, const float* __restrict__ bhh1,
    const float* __restrict__ bih2, const float* __restrict__ bhh2,
    unsigned short* __restrict__ hst,        // [3][25][64][512]
    unsigned int* __restrict__ flags)        // [3][24][32]
{
    extern __shared__ unsigned short lB[];   // [64][K+8]
    const int bid = blockIdx.x;
    const int layer = bid >> 5;
    const int lbid = bid & 31;
    const int j0 = lbid * 16;
    const int tid = threadIdx.x;
    const int lane = tid & 63, w = tid >> 6;       // wave w: batch rows w*16..
    const int lrow = lane & 15, lk = (lane >> 4) * 8;

    const int K = (layer == 0) ? 512 : 1024;
    const int stride = K + 8;
    const size_t wbase = (layer == 0) ? 0
                       : (layer == 1) ? (size_t)32 * 64 * 512
                                      : (size_t)32 * 64 * 512 + (size_t)32 * 64 * 1024;
    const unsigned short* Wblk = Wpk + wbase + (size_t)lbid * 64 * K;

    // ---- stage W once into LDS (persistent across all 24 timesteps)
    {
        const int kshift = (layer == 0) ? 6 : 7;      // chunks-per-row = K/8
        const int ckm1 = (K >> 3) - 1;
        const int total = 64 << kshift;               // 64 * K/8
        for (int idx = tid; idx < total; idx += 256) {
            int row = idx >> kshift, kc = (idx & ckm1) * 8;
            *(bf16x8*)&lB[row * stride + kc] =
                *(const bf16x8*)&Wblk[(size_t)row * K + kc];
        }
    }
    __syncthreads();

    unsigned short* hl = hst + (size_t)layer * 25 * 64 * 512;
    const unsigned short* hlow =
        (layer > 0) ? hst + (size_t)(layer - 1) * 25 * 64 * 512 : nullptr;

    // per-lane bias (layers 1,2), constant over t: j = j0+lrow, gates q
    float pb[4] = {0.f, 0.f, 0.f, 0.f};
    if (layer == 1) {
        #pragma unroll
        for (int q = 0; q < 4; ++q)
            pb[q] = bih1[q * 512 + j0 + lrow] + bhh1[q * 512 + j0 + lrow];
    } else if (layer == 2) {
        #pragma unroll
        for (int q = 0; q < 4; ++q)
            pb[q] = bih2[q * 512 + j0 + lrow] + bhh2[q * 512 + j0 + lrow];
    }

    float creg[4] = {0.f, 0.f, 0.f, 0.f};

    for (int t = 0; t < 24; ++t) {
        // ---- wait for dependencies: poll single-writer flags in parallel
        if (w == 0) {
            const unsigned int* f1 = nullptr;
            const unsigned int* f2 = nullptr;
            if (layer == 0) {
                if (t > 0) f1 = flags + (0 * 24 + (t - 1)) * 32;
            } else {
                f1 = flags + ((layer - 1) * 24 + t) * 32;
                if (t > 0) f2 = flags + (layer * 24 + (t - 1)) * 32;
            }
            if (f1) {
                int idx = lane & 31;
                while (true) {
                    unsigned a = __hip_atomic_load(&f1[idx], __ATOMIC_ACQUIRE,
                                                   __HIP_MEMORY_SCOPE_AGENT);
                    unsigned b = f2 ? __hip_atomic_load(&f2[idx], __ATOMIC_ACQUIRE,
                                                        __HIP_MEMORY_SCOPE_AGENT)
                                    : 1u;
                    if (__all(a != 0 && b != 0)) break;
                    __builtin_amdgcn_s_sleep(1);
                }
                __threadfence();    // L1 invalidate so h reads see remote writes
            }
        }
        __syncthreads();

        const unsigned short* A0 = (layer == 0)
            ? hl + (size_t)t * 64 * 512              // h_{0,t-1}
            : hlow + (size_t)(t + 1) * 64 * 512;     // h_{l-1,t}
        const unsigned short* A1 = (layer == 0)
            ? nullptr
            : hl + (size_t)t * 64 * 512;             // h_{l,t-1}

        f32x4 acc[4] = {};
        const int arow = (w * 16 + lrow) * 512;

        // double-buffered A-fragment ingest: 8 loads in flight
        bf16x8 afA[8], afB[8];
        #pragma unroll
        for (int u = 0; u < 8; ++u) {
            int kg = u * 32 + lk;
            afA[u] = *(const bf16x8*)((kg < 512) ? &A0[arow + kg]
                                                 : &A1[arow + kg - 512]);
        }
        for (int kb = 0; kb < K; kb += 256) {
            bf16x8* cur = ((kb >> 8) & 1) ? afB : afA;
            bf16x8* nxt = ((kb >> 8) & 1) ? afA : afB;
            if (kb + 256 < K) {
                #pragma unroll
                for (int u = 0; u < 8; ++u) {
                    int kg = kb + 256 + u * 32 + lk;
                    nxt[u] = *(const bf16x8*)((kg < 512) ? &A0[arow + kg]
                                                         : &A1[arow + kg - 512]);
                }
            }
            #pragma unroll
            for (int u = 0; u < 8; ++u) {
                int ksl = kb + u * 32 + lk;
                #pragma unroll
                for (int q = 0; q < 4; ++q) {
                    bf16x8 bq = *(const bf16x8*)&lB[(q * 16 + lrow) * stride + ksl];
                    acc[q] = __builtin_amdgcn_mfma_f32_16x16x32_bf16(
                        cur[u], bq, acc[q], 0, 0, 0);
                }
            }
        }

        // ---- fused LSTM pointwise epilogue
        int j = j0 + lrow;
        #pragma unroll
        for (int r = 0; r < 4; ++r) {
            int b = w * 16 + ((lane >> 4) << 2) + r;
            float g[4];
            #pragma unroll
            for (int q = 0; q < 4; ++q) {
                float p = (layer == 0)
                    ? G0[((size_t)t * 64 + b) * 2048 + q * 512 + j]
                    : pb[q];
                g[q] = acc[q][r] + p;
            }
            float ig = sigmoidf(g[0]);
            float fg = sigmoidf(g[1]);
            float gg = tanhf(g[2]);
            float og = sigmoidf(g[3]);
            float cn = fg * creg[r] + ig * gg;
            creg[r] = cn;
            float h = og * tanhf(cn);
            hl[((size_t)(t + 1) * 64 + b) * 512 + j] = f2b(h);
        }
        __syncthreads();           // all waves' h stores drained before release
        if (tid == 0) {
            __hip_atomic_store(&flags[(layer * 24 + t) * 32 + lbid], 1u,
                               __ATOMIC_RELEASE, __HIP_MEMORY_SCOPE_AGENT);
        }
    }
}

// ---------------- launch ----------------
extern "C" void kernel_launch(void* const* d_in, const int* in_sizes, int n_in,
                              void* d_out, int out_size, void* d_ws, size_t ws_size,
                              hipStream_t stream) {
    const float* qf  = (const float*)d_in[0];
    const float* imf = (const float*)d_in[1];
    const int*   seq = (const int*)d_in[2];
    const float* emb = (const float*)d_in[3];
    // d_in[4..6] dead code
    const float* fcW = (const float*)d_in[7];
    const float* fcb = (const float*)d_in[8];
    const float* Wih[3] = {(const float*)d_in[9],  (const float*)d_in[13], (const float*)d_in[17]};
    const float* Whh[3] = {(const float*)d_in[10], (const float*)d_in[14], (const float*)d_in[18]};
    const float* bih[3] = {(const float*)d_in[11], (const float*)d_in[15], (const float*)d_in[19]};
    const float* bhh[3] = {(const float*)d_in[12], (const float*)d_in[16], (const float*)d_in[20]};

    char* ws = (char*)d_ws;
    unsigned short* X     = (unsigned short*)(ws + 0);          // 3,932,160
    float*          G0    = (float*)(ws + 3932160);             // 12,582,912
    unsigned short* hst   = (unsigned short*)(ws + 16515072);   // 4,915,200
    unsigned int*   flags = (unsigned int*)(ws + 21430272);     // 3*24*32*4 = 9216
    unsigned short* Wpk   = (unsigned short*)(ws + 21440000);   // 10,485,760
    unsigned short* Wih0b = (unsigned short*)(ws + 31925760);   // 5,242,880
    unsigned short* fcWb  = (unsigned short*)(ws + 37168640);   // 32,768,000 (end ~70MB)

    // zero: flags + h slot 0 of each layer
    hipMemsetAsync(flags, 0, 9216, stream);
    for (int l = 0; l < 3; ++l)
        hipMemsetAsync(hst + (size_t)l * 25 * 64 * 512, 0, 64 * 512 * 2, stream);

    // weight conversions
    { int n4 = 2048 * 1280 / 4;
      cvt_bf16<<<(n4 + 255) / 256, 256, 0, stream>>>(Wih[0], Wih0b, n4); }
    { int n4 = 32000 * 512 / 4;
      cvt_bf16<<<(n4 + 255) / 256, 256, 0, stream>>>(fcW, fcWb, n4); }
    pack_w<<<3 * 32 * 64, 128, 0, stream>>>(Whh[0], Wih[1], Whh[1], Wih[2], Whh[2], Wpk);

    build_x<<<1536, 256, 0, stream>>>(qf, imf, seq, emb, X);

    // G0 = X @ W_ih0^T + b_ih0 + b_hh0 : M=1536, N=2048, K=1280 -> 12x16=192 wg
    gemm128<0><<<192, 256, 0, stream>>>(
        X, 1280, Wih0b, 1280, 1280, bih[0], bhh[0], G0, 2048, 12, 192 / 8);

    // persistent recurrence: dynamic LDS = 64 * (1024+8) * 2 = 132096 B
    lstm_wave<<<96, 256, 132096, stream>>>(
        Wpk, G0, bih[1], bhh[1], bih[2], bhh[2], hst, flags);

    // logits: hst[2] slots 1..24 = h2 rows m=t*64+b ; M=1536,N=32000,K=512
    const unsigned short* h2 = hst + (size_t)2 * 25 * 64 * 512 + 64 * 512;
    gemm128<1><<<3000, 256, 0, stream>>>(
        h2, 512, fcWb, 512, 512, fcb, nullptr, (float*)d_out, 32000, 12, 3000 / 8);
}

// Round 6
// 376.418 us; speedup vs baseline: 5.1460x; 1.3431x over previous
//
#include <hip/hip_runtime.h>
#include <hip/hip_bf16.h>
#include <stdint.h>

// Answer_Decoder: B=64, T=24, H=512, V=32000, E=256. All I/O float32.
// Attention is dead code (softmax over size-1 axis => ctx == cat(q,img)).
// Pipeline:
//   0) cvt Wih0/fcW f32->bf16; pack recurrent weights bf16 per-block
//   1) build_x: X[1536][1280] bf16
//   2) G0 = X @ W_ih0^T + b_ih0 + b_hh0 (f32, gemm128<0>)
//   3) lstm_wave: ONE persistent kernel, 96 blocks (32/layer), (t,layer)
//      wavefront. Cross-XCD handoff via COHERENT-BYPASS (sc0 sc1) h
//      stores/loads (write-through to / read from L3 = coherence point),
//      single-writer RELAXED agent flags. No fences, no L2 inv/wb.
//      W persistent in LDS; c in registers; h per-t slots (no WAR).
//   4) fc: hst[2] @ fc_W^T + fc_b -> out[b][t][v] f32 (gemm128<1>, XCD swizzle)

typedef short bf16x8 __attribute__((ext_vector_type(8)));
typedef float f32x4 __attribute__((ext_vector_type(4)));

#define NBLK_L 32   // blocks per layer in lstm_wave

__device__ __forceinline__ unsigned short f2b(float f) {
    uint32_t u = __builtin_bit_cast(uint32_t, f);
    uint32_t r = u + 0x7FFFu + ((u >> 16) & 1u);
    return (unsigned short)(r >> 16);
}
__device__ __forceinline__ float sigmoidf(float x) {
    return 1.0f / (1.0f + expf(-x));
}

// ---------------- f32 -> bf16 convert ----------------
__global__ __launch_bounds__(256) void cvt_bf16(
    const float* __restrict__ src, unsigned short* __restrict__ dst, int n4)
{
    int i = blockIdx.x * 256 + threadIdx.x;
    if (i >= n4) return;
    f32x4 v = *(const f32x4*)&src[i * 4];
    unsigned short o[4];
    #pragma unroll
    for (int j = 0; j < 4; ++j) o[j] = f2b(v[j]);
    *(uint64_t*)&dst[i * 4] = *(uint64_t*)o;
}

// ---------------- pack recurrent weights (bf16, per-block contiguous) -------
// Wpk layout: l0 [32][64][512] ; l1 [32][64][1024] ; l2 [32][64][1024]
// block row r in [0,64): gate q=r>>4, jj=r&15; source gate-row = q*512+lbid*16+jj
__global__ __launch_bounds__(128) void pack_w(
    const float* __restrict__ Whh0,
    const float* __restrict__ Wih1, const float* __restrict__ Whh1,
    const float* __restrict__ Wih2, const float* __restrict__ Whh2,
    unsigned short* __restrict__ Wpk)
{
    int gid = blockIdx.x;                 // 3*32*64 = 6144
    int layer = gid / (32 * 64);
    int rem = gid % (32 * 64);
    int lbid = rem >> 6, r = rem & 63;
    int q = r >> 4, jj = r & 15;
    int grow = q * 512 + lbid * 16 + jj;
    int K = (layer == 0) ? 512 : 1024;
    size_t wbase = (layer == 0) ? 0
                 : (layer == 1) ? (size_t)32 * 64 * 512
                                : (size_t)32 * 64 * 512 + (size_t)32 * 64 * 1024;
    unsigned short* dst = Wpk + wbase + ((size_t)lbid * 64 + r) * K;
    const float *s0, *s1 = nullptr;
    if (layer == 0)      { s0 = Whh0 + (size_t)grow * 512; }
    else if (layer == 1) { s0 = Wih1 + (size_t)grow * 512; s1 = Whh1 + (size_t)grow * 512; }
    else                 { s0 = Wih2 + (size_t)grow * 512; s1 = Whh2 + (size_t)grow * 512; }
    {
        int k4 = threadIdx.x;             // 128 threads x 4 = 512
        f32x4 v = *(const f32x4*)&s0[k4 * 4];
        unsigned short o[4];
        #pragma unroll
        for (int j = 0; j < 4; ++j) o[j] = f2b(v[j]);
        *(uint64_t*)&dst[k4 * 4] = *(uint64_t*)o;
    }
    if (s1) {
        int k4 = threadIdx.x;
        f32x4 v = *(const f32x4*)&s1[k4 * 4];
        unsigned short o[4];
        #pragma unroll
        for (int j = 0; j < 4; ++j) o[j] = f2b(v[j]);
        *(uint64_t*)&dst[512 + k4 * 4] = *(uint64_t*)o;
    }
}

// ---------------- build X ----------------
__global__ __launch_bounds__(256) void build_x(
    const float* __restrict__ qf,   // [64][512]
    const float* __restrict__ imf,  // [64][512]
    const int* __restrict__ seq,    // [64][24]
    const float* __restrict__ emb,  // [32000][256]
    unsigned short* __restrict__ X) // [1536][1280] bf16, row m = t*64+b
{
    int r = blockIdx.x;
    int t = r >> 6, b = r & 63;
    int tok = seq[b * 24 + t];
    for (int e = threadIdx.x; e < 1280; e += 256) {
        float v;
        if (e < 256)      v = emb[(size_t)tok * 256 + e];
        else if (e < 768) v = qf[b * 512 + (e - 256)];
        else              v = imf[b * 512 + (e - 768)];
        X[(size_t)r * 1280 + e] = f2b(v);
    }
}

// ---------------- 128x128 MFMA GEMM: C = A @ W^T + bias ----------------
// 1D grid (nwg = mblocks * nblocks, divisible by 8), XCD-bijective remap.
// OUT_MODE 0: f32 out [M][ldo], bias = bias0[n]+bias1[n]
// OUT_MODE 1: f32 out with m=(t*64+b) -> out[(b*24+t)*ldo + n], bias=bias0[n]
template<int OUT_MODE>
__global__ __launch_bounds__(256) void gemm128(
    const unsigned short* __restrict__ A, int lda,
    const unsigned short* __restrict__ W, int ldb,
    int K,
    const float* __restrict__ bias0,
    const float* __restrict__ bias1,
    float* __restrict__ outf, int ldo, int mblocks, int xcdq)
{
    __shared__ unsigned short lA[128 * 72];
    __shared__ unsigned short lB[128 * 72];
    int lin = blockIdx.x;
    int wg = (lin & 7) * xcdq + (lin >> 3);     // contiguous chunk per XCD
    const int m0 = (wg % mblocks) * 128, n0 = (wg / mblocks) * 128;
    const int tid = threadIdx.x;
    const int lane = tid & 63, wid = tid >> 6;
    const int wm = wid >> 1, wn = wid & 1;

    f32x4 acc[4][4] = {};

    for (int kt = 0; kt < K; kt += 64) {
        #pragma unroll
        for (int c = 0; c < 4; ++c) {
            int chunk = tid + c * 256;
            int row = chunk >> 3, kc = (chunk & 7) * 8;
            *(bf16x8*)&lA[row * 72 + kc] =
                *(const bf16x8*)&A[(size_t)(m0 + row) * lda + kt + kc];
            *(bf16x8*)&lB[row * 72 + kc] =
                *(const bf16x8*)&W[(size_t)(n0 + row) * ldb + kt + kc];
        }
        __syncthreads();
        #pragma unroll
        for (int ks = 0; ks < 64; ks += 32) {
            int kl = ks + ((lane >> 4) << 3);
            bf16x8 af[4], bfr[4];
            #pragma unroll
            for (int i = 0; i < 4; ++i)
                af[i] = *(const bf16x8*)&lA[(wm * 64 + i * 16 + (lane & 15)) * 72 + kl];
            #pragma unroll
            for (int j = 0; j < 4; ++j)
                bfr[j] = *(const bf16x8*)&lB[(wn * 64 + j * 16 + (lane & 15)) * 72 + kl];
            #pragma unroll
            for (int i = 0; i < 4; ++i)
                #pragma unroll
                for (int j = 0; j < 4; ++j)
                    acc[i][j] = __builtin_amdgcn_mfma_f32_16x16x32_bf16(
                        af[i], bfr[j], acc[i][j], 0, 0, 0);
        }
        __syncthreads();
    }

    #pragma unroll
    for (int i = 0; i < 4; ++i) {
        #pragma unroll
        for (int j = 0; j < 4; ++j) {
            int n = n0 + wn * 64 + j * 16 + (lane & 15);
            float bias = (OUT_MODE == 0) ? bias0[n] + bias1[n] : bias0[n];
            #pragma unroll
            for (int r = 0; r < 4; ++r) {
                int m = m0 + wm * 64 + i * 16 + ((lane >> 4) << 2) + r;
                float v = acc[i][j][r] + bias;
                if (OUT_MODE == 0) {
                    outf[(size_t)m * ldo + n] = v;
                } else {
                    int b = m & 63, t = m >> 6;
                    outf[(size_t)(b * 24 + t) * ldo + n] = v;
                }
            }
        }
    }
}

// ---- sc0 sc1 (device-coherent, L2-bypass) primitives for lstm_wave ----
#define ISSUE_CHUNK(buf, kb0)                                                 \
    {                                                                         \
        _Pragma("unroll")                                                     \
        for (int u_ = 0; u_ < 8; ++u_) {                                      \
            int kg_ = (kb0) + u_ * 32 + lk;                                   \
            const unsigned short* ap_ = (kg_ < 512)                           \
                ? &A0[arow + kg_] : &A1[arow + kg_ - 512];                    \
            asm volatile("global_load_dwordx4 %0, %1, off sc0 sc1"            \
                         : "=v"(buf[u_]) : "v"(ap_) : "memory");              \
        }                                                                     \
    }
#define MFMA_CHUNK(buf, kb0)                                                  \
    {                                                                         \
        _Pragma("unroll")                                                     \
        for (int u_ = 0; u_ < 8; ++u_) {                                      \
            int ksl_ = (kb0) + u_ * 32 + lk;                                  \
            _Pragma("unroll")                                                 \
            for (int q_ = 0; q_ < 4; ++q_) {                                  \
                bf16x8 bq_ = *(const bf16x8*)&lB[(q_ * 16 + lrow) * stride + ksl_]; \
                acc[q_] = __builtin_amdgcn_mfma_f32_16x16x32_bf16(            \
                    buf[u_], bq_, acc[q_], 0, 0, 0);                          \
            }                                                                 \
        }                                                                     \
    }
#define VM_WAIT8 { asm volatile("s_waitcnt vmcnt(8)" ::: "memory");           \
                   __builtin_amdgcn_sched_barrier(0); }
#define VM_WAIT0 { asm volatile("s_waitcnt vmcnt(0)" ::: "memory");           \
                   __builtin_amdgcn_sched_barrier(0); }

// ---------------- persistent wavefront LSTM recurrence ----------------
// 96 blocks x 256 threads. Block bid: layer = bid>>5, lbid = bid&31,
// j-slice = [lbid*16, lbid*16+16). Per cell: gates[64b x 64rows] =
// A[64xK] @ Wblk[64xK]^T. A via sc0sc1 loads (read L3 directly);
// h stores sc0sc1 (write through to L3); W persistent in LDS;
// flags single-writer RELAXED agent atomics. No fences anywhere.
__global__ __launch_bounds__(256, 1) void lstm_wave(
    const unsigned short* __restrict__ Wpk,
    const float* __restrict__ G0,            // [24][64][2048]
    const float* __restrict__ bih1, const float* __restrict__ bhh1,
    const float* __restrict__ bih2, const float* __restrict__ bhh2,
    unsigned short* __restrict__ hst,        // [3][25][64][512]
    unsigned int* __restrict__ flags)        // [3][24][32]
{
    extern __shared__ unsigned short lB[];   // [64][K+8]
    const int bid = blockIdx.x;
    const int layer = bid >> 5;
    const int lbid = bid & 31;
    const int j0 = lbid * 16;
    const int tid = threadIdx.x;
    const int lane = tid & 63, w = tid >> 6;       // wave w: batch rows w*16..
    const int lrow = lane & 15, lk = (lane >> 4) * 8;

    const int K = (layer == 0) ? 512 : 1024;
    const int stride = K + 8;
    const size_t wbase = (layer == 0) ? 0
                       : (layer == 1) ? (size_t)32 * 64 * 512
                                      : (size_t)32 * 64 * 512 + (size_t)32 * 64 * 1024;
    const unsigned short* Wblk = Wpk + wbase + (size_t)lbid * 64 * K;

    // ---- stage W once into LDS (persistent across all 24 timesteps)
    {
        const int kshift = (layer == 0) ? 6 : 7;      // chunks-per-row = K/8
        const int ckm1 = (K >> 3) - 1;
        const int total = 64 << kshift;               // 64 * K/8
        for (int idx = tid; idx < total; idx += 256) {
            int row = idx >> kshift, kc = (idx & ckm1) * 8;
            *(bf16x8*)&lB[row * stride + kc] =
                *(const bf16x8*)&Wblk[(size_t)row * K + kc];
        }
    }
    __syncthreads();

    unsigned short* hl = hst + (size_t)layer * 25 * 64 * 512;
    const unsigned short* hlow =
        (layer > 0) ? hst + (size_t)(layer - 1) * 25 * 64 * 512 : nullptr;

    // per-lane bias (layers 1,2), constant over t: j = j0+lrow, gates q
    float pb[4] = {0.f, 0.f, 0.f, 0.f};
    if (layer == 1) {
        #pragma unroll
        for (int q = 0; q < 4; ++q)
            pb[q] = bih1[q * 512 + j0 + lrow] + bhh1[q * 512 + j0 + lrow];
    } else if (layer == 2) {
        #pragma unroll
        for (int q = 0; q < 4; ++q)
            pb[q] = bih2[q * 512 + j0 + lrow] + bhh2[q * 512 + j0 + lrow];
    }

    float creg[4] = {0.f, 0.f, 0.f, 0.f};

    for (int t = 0; t < 24; ++t) {
        // ---- wait for dependencies: relaxed poll, split across lane halves
        {
            const unsigned int* f1 = nullptr;
            const unsigned int* f2 = nullptr;
            if (layer == 0) {
                if (t > 0) f1 = flags + (0 * 24 + (t - 1)) * 32;
            } else {
                f1 = flags + ((layer - 1) * 24 + t) * 32;
                if (t > 0) f2 = flags + (layer * 24 + (t - 1)) * 32;
            }
            if (w == 0 && f1) {
                const unsigned int* fp = (lane < 32) ? f1 : (f2 ? f2 : f1);
                int idx = lane & 31;
                while (true) {
                    unsigned v = __hip_atomic_load((unsigned int*)&fp[idx],
                                                   __ATOMIC_RELAXED,
                                                   __HIP_MEMORY_SCOPE_AGENT);
                    if (__all(v != 0)) break;
                    __builtin_amdgcn_s_sleep(1);
                }
            }
        }
        __syncthreads();

        const unsigned short* A0 = (layer == 0)
            ? hl + (size_t)t * 64 * 512              // h_{0,t-1}
            : hlow + (size_t)(t + 1) * 64 * 512;     // h_{l-1,t}
        const unsigned short* A1 = (layer == 0)
            ? A0                                      // unused (K=512)
            : hl + (size_t)t * 64 * 512;             // h_{l,t-1}

        f32x4 acc[4] = {};
        const int arow = (w * 16 + lrow) * 512;

        // ---- K loop: 2-deep chunk pipeline, sc0sc1 loads, counted vmcnt
        bf16x8 bufA[8], bufB[8];
        ISSUE_CHUNK(bufA, 0);
        for (int kb = 0; kb < K; kb += 512) {
            const bool haveB = (kb + 256 < K);
            if (haveB) { ISSUE_CHUNK(bufB, kb + 256); }
            if (haveB) { VM_WAIT8 } else { VM_WAIT0 }
            MFMA_CHUNK(bufA, kb);
            if (kb + 512 < K) { ISSUE_CHUNK(bufA, kb + 512); }
            if (haveB) {
                if (kb + 512 < K) { VM_WAIT8 } else { VM_WAIT0 }
                MFMA_CHUNK(bufB, kb + 256);
            }
        }

        // ---- fused LSTM pointwise epilogue; h stores write through to L3
        int j = j0 + lrow;
        #pragma unroll
        for (int r = 0; r < 4; ++r) {
            int b = w * 16 + ((lane >> 4) << 2) + r;
            float g[4];
            #pragma unroll
            for (int q = 0; q < 4; ++q) {
                float p = (layer == 0)
                    ? G0[((size_t)t * 64 + b) * 2048 + q * 512 + j]
                    : pb[q];
                g[q] = acc[q][r] + p;
            }
            float ig = sigmoidf(g[0]);
            float fg = sigmoidf(g[1]);
            float gg = tanhf(g[2]);
            float og = sigmoidf(g[3]);
            float cn = fg * creg[r] + ig * gg;
            creg[r] = cn;
            float h = og * tanhf(cn);
            unsigned int hb = (unsigned int)f2b(h);
            unsigned short* hp = &hl[((size_t)(t + 1) * 64 + b) * 512 + j];
            asm volatile("global_store_short %0, %1, off sc0 sc1"
                         :: "v"(hp), "v"(hb) : "memory");
        }
        // drain this wave's write-through stores, then block-wide barrier
        asm volatile("s_waitcnt vmcnt(0)" ::: "memory");
        __syncthreads();
        if (tid == 0) {
            __hip_atomic_store(&flags[(layer * 24 + t) * 32 + lbid], 1u,
                               __ATOMIC_RELAXED, __HIP_MEMORY_SCOPE_AGENT);
        }
    }
}

// ---------------- launch ----------------
extern "C" void kernel_launch(void* const* d_in, const int* in_sizes, int n_in,
                              void* d_out, int out_size, void* d_ws, size_t ws_size,
                              hipStream_t stream) {
    const float* qf  = (const float*)d_in[0];
    const float* imf = (const float*)d_in[1];
    const int*   seq = (const int*)d_in[2];
    const float* emb = (const float*)d_in[3];
    // d_in[4..6] dead code
    const float* fcW = (const float*)d_in[7];
    const float* fcb = (const float*)d_in[8];
    const float* Wih[3] = {(const float*)d_in[9],  (const float*)d_in[13], (const float*)d_in[17]};
    const float* Whh[3] = {(const float*)d_in[10], (const float*)d_in[14], (const float*)d_in[18]};
    const float* bih[3] = {(const float*)d_in[11], (const float*)d_in[15], (const float*)d_in[19]};
    const float* bhh[3] = {(const float*)d_in[12], (const float*)d_in[16], (const float*)d_in[20]};

    char* ws = (char*)d_ws;
    unsigned short* X     = (unsigned short*)(ws + 0);          // 3,932,160
    float*          G0    = (float*)(ws + 3932160);             // 12,582,912
    unsigned short* hst   = (unsigned short*)(ws + 16515072);   // 4,915,200
    unsigned int*   flags = (unsigned int*)(ws + 21430272);     // 3*24*32*4 = 9216
    unsigned short* Wpk   = (unsigned short*)(ws + 21440000);   // 10,485,760
    unsigned short* Wih0b = (unsigned short*)(ws + 31925760);   // 5,242,880
    unsigned short* fcWb  = (unsigned short*)(ws + 37168640);   // 32,768,000 (end ~70MB)

    // zero: flags + h slot 0 of each layer
    hipMemsetAsync(flags, 0, 9216, stream);
    for (int l = 0; l < 3; ++l)
        hipMemsetAsync(hst + (size_t)l * 25 * 64 * 512, 0, 64 * 512 * 2, stream);

    // weight conversions
    { int n4 = 2048 * 1280 / 4;
      cvt_bf16<<<(n4 + 255) / 256, 256, 0, stream>>>(Wih[0], Wih0b, n4); }
    { int n4 = 32000 * 512 / 4;
      cvt_bf16<<<(n4 + 255) / 256, 256, 0, stream>>>(fcW, fcWb, n4); }
    pack_w<<<3 * 32 * 64, 128, 0, stream>>>(Whh[0], Wih[1], Whh[1], Wih[2], Whh[2], Wpk);

    build_x<<<1536, 256, 0, stream>>>(qf, imf, seq, emb, X);

    // G0 = X @ W_ih0^T + b_ih0 + b_hh0 : M=1536, N=2048, K=1280 -> 12x16=192 wg
    gemm128<0><<<192, 256, 0, stream>>>(
        X, 1280, Wih0b, 1280, 1280, bih[0], bhh[0], G0, 2048, 12, 192 / 8);

    // persistent recurrence: dynamic LDS = 64 * (1024+8) * 2 = 132096 B
    lstm_wave<<<96, 256, 132096, stream>>>(
        Wpk, G0, bih[1], bhh[1], bih[2], bhh[2], hst, flags);

    // logits: hst[2] slots 1..24 = h2 rows m=t*64+b ; M=1536,N=32000,K=512
    const unsigned short* h2 = hst + (size_t)2 * 25 * 64 * 512 + 64 * 512;
    gemm128<1><<<3000, 256, 0, stream>>>(
        h2, 512, fcWb, 512, 512, fcb, nullptr, (float*)d_out, 32000, 12, 3000 / 8);
}